// Round 5
// baseline (251.370 us; speedup 1.0000x reference)
//
#include <hip/hip_runtime.h>

#define NKW   65536
#define NDOC  65536
#define NSEG  131072          // kw segs then doc segs
#define NE    1048576
#define CHUNK 4096            // edges per partition block
#define NBLK  (NE / CHUNK)    // 256

typedef unsigned long long u64;
typedef unsigned short     u16;
typedef unsigned int       u32;

typedef __attribute__((ext_vector_type(8))) short short8;   // 8 bf16 (4 VGPRs)
typedef __attribute__((ext_vector_type(4))) float f32x4;    // MFMA acc

union U8 { short8 v; u64 u[2]; short s[8]; };

__device__ __forceinline__ u16 f2bf(float f) {              // RNE f32->bf16
    u32 u = __builtin_bit_cast(u32, f);
    u = (u + 0x7fffu + ((u >> 16) & 1u)) >> 16;
    return (u16)u;
}
__device__ __forceinline__ float bf2f(u16 h) {
    return __builtin_bit_cast(float, (u32)h << 16);
}

// ---------------- workspace layout (bytes) ----------------
#define BUFA_OFF 0ull
#define BUFB_OFF 16777216ull
#define BUFC_OFF 33554432ull
#define WF_OFF   50331648ull            // 7 * 32KB fragment-packed weights
#define CSR_OFF  51380224ull            // 2*NE ints = 8 MB
#define CNT_OFF  59768832ull            // NSEG ints
#define AUX_OFF  60293120ull            // bhist[512] | bfill[512] | bbase[512]
#define OFF_OFF  60821504ull            // NSEG ints
#define DIS_OFF  61345792ull            // NSEG floats

// ---------------- CSR build (bucketed, write-local) ----------------
__global__ __launch_bounds__(256) void bhist_k(const int* __restrict__ src,
                                               const int* __restrict__ dst,
                                               int* __restrict__ bhist) {
    __shared__ int h[512];
    int tid = threadIdx.x;
    for (int i = tid; i < 512; i += 256) h[i] = 0;
    __syncthreads();
    int e0 = blockIdx.x * CHUNK;
    for (int i = tid; i < CHUNK; i += 256) {
        int s = src[e0 + i];
        int d = dst[e0 + i] - NKW;
        atomicAdd(&h[s >> 8], 1);
        atomicAdd(&h[256 + (d >> 8)], 1);
    }
    __syncthreads();
    for (int i = tid; i < 512; i += 256)
        if (h[i]) atomicAdd(&bhist[i], h[i]);
}

__global__ void bscan_k(const int* __restrict__ bhist, int* __restrict__ bbase) {
    __shared__ int s[512];
    int tid = threadIdx.x;
    int v = bhist[tid];
    s[tid] = v;
    __syncthreads();
    for (int d = 1; d < 512; d <<= 1) {
        int t = (tid >= d) ? s[tid - d] : 0;
        __syncthreads();
        s[tid] += t;
        __syncthreads();
    }
    bbase[tid] = s[tid] - v;      // exclusive
}

__global__ __launch_bounds__(256) void part_k(const int* __restrict__ src,
                                              const int* __restrict__ dst,
                                              const int* __restrict__ bbase,
                                              int* __restrict__ bfill,
                                              u32* __restrict__ pairs) {
    __shared__ int h[512], sc[512], base[512];
    __shared__ u32 staged[2 * CHUNK];
    const int tid = threadIdx.x;
    for (int i = tid; i < 512; i += 256) h[i] = 0;
    __syncthreads();

    const int e0 = blockIdx.x * CHUNK;
    int se[16], de[16];
    #pragma unroll
    for (int j = 0; j < 16; ++j) {
        int e = e0 + tid + j * 256;           // coalesced
        se[j] = src[e];
        de[j] = dst[e] - NKW;
        atomicAdd(&h[se[j] >> 8], 1);
        atomicAdd(&h[256 + (de[j] >> 8)], 1);
    }
    __syncthreads();

    sc[tid] = h[tid];
    __syncthreads();
    for (int d = 1; d < 256; d <<= 1) {
        int t = (tid >= d) ? sc[tid - d] : 0;
        __syncthreads();
        sc[tid] += t;
        __syncthreads();
    }
    sc[256 + tid] = h[256 + tid];
    __syncthreads();
    for (int d = 1; d < 256; d <<= 1) {
        int t = (tid >= d) ? sc[256 + tid - d] : 0;
        __syncthreads();
        sc[256 + tid] += t;
        __syncthreads();
    }

    for (int i = tid; i < 512; i += 256) {
        base[i] = bbase[i] + atomicAdd(&bfill[i], h[i]);
        sc[i] -= h[i];
        h[i] = 0;
    }
    __syncthreads();

    #pragma unroll
    for (int j = 0; j < 16; ++j) {
        int bk = se[j] >> 8;
        int r  = atomicAdd(&h[bk], 1);
        staged[sc[bk] + r] = ((u32)(se[j] & 255) << 16) | (u32)de[j];
        int bd = 256 + (de[j] >> 8);
        int r2 = atomicAdd(&h[bd], 1);
        staged[CHUNK + sc[bd] + r2] = ((u32)(de[j] & 255) << 16) | (u32)se[j];
    }
    __syncthreads();

    for (int i = tid; i < 512; i += 256) {
        int n = h[i];
        int so = (i < 256 ? 0 : CHUNK) + sc[i];
        u32* dp = pairs + base[i];
        for (int j = 0; j < n; ++j) dp[j] = staged[so + j];
    }
}

__global__ __launch_bounds__(256) void build_k(const u32* __restrict__ pairs,
                                               const int* __restrict__ bbase,
                                               const int* __restrict__ bfill,
                                               int* __restrict__ off, int* __restrict__ cnt,
                                               float* __restrict__ dis, int* __restrict__ csr) {
    __shared__ int lcnt[256], lsc[256];
    const int b   = blockIdx.x;
    const int tid = threadIdx.x;
    const int start = bbase[b];
    const int size  = bfill[b];
    lcnt[tid] = 0;
    __syncthreads();
    for (int i = tid; i < size; i += 256)
        atomicAdd(&lcnt[(pairs[start + i] >> 16) & 255], 1);
    __syncthreads();
    lsc[tid] = lcnt[tid];
    __syncthreads();
    for (int d = 1; d < 256; d <<= 1) {
        int t = (tid >= d) ? lsc[tid - d] : 0;
        __syncthreads();
        lsc[tid] += t;
        __syncthreads();
    }
    const int myexc = lsc[tid] - lcnt[tid];
    const int seg = (b < 256) ? (b * 256 + tid) : (NKW + (b - 256) * 256 + tid);
    off[seg] = start + myexc;
    cnt[seg] = lcnt[tid];
    dis[seg] = rsqrtf((float)(lcnt[tid] + 1));
    lsc[tid]  = myexc;
    lcnt[tid] = 0;
    __syncthreads();
    for (int i = tid; i < size; i += 256) {
        u32 p = pairs[start + i];
        int key = (p >> 16) & 255;
        int r = atomicAdd(&lcnt[key], 1);
        csr[start + lsc[key] + r] = (int)(p & 0xFFFF);
    }
}

// ---------------- weight fragment pre-pack (fp32 [K][128] -> bf16 MFMA frags) ----
struct PrepArgs { const float* w[7]; int K[7]; };

__global__ void prepw_k(PrepArgs pa, short8* __restrict__ outb) {
    int m  = blockIdx.x >> 5;
    int bk = blockIdx.x & 31;
    int kc = bk >> 3, ct = bk & 7;
    int l  = threadIdx.x;
    int K  = pa.K[m];
    const float* W = pa.w[m];
    U8 o;
    #pragma unroll
    for (int i = 0; i < 8; ++i) {
        int k   = kc * 32 + 4 * (l >> 4) + (i & 3) + 16 * (i >> 2);
        int col = ct * 16 + (l & 15);
        float v = (k < K) ? W[(size_t)k * 128 + col] : 0.f;
        o.s[i] = (short)f2bf(v);
    }
    outb[(size_t)m * 2048 + bk * 64 + l] = o.v;
}

// ---------------- MFMA GEMM: C[65536,128] = op(A[65536,K] @ W[K,128] + b) --------
template<int K, bool AF32, bool RELU, bool OUTF32>
__global__ __launch_bounds__(256) void mgemm_k(
        const void* __restrict__ Av, const short8* __restrict__ wf,
        const float* __restrict__ bias, void* __restrict__ Cv) {
    const int tid = threadIdx.x;
    const int w  = tid >> 6;
    const int l  = tid & 63;
    const int lr = l & 15;
    const int q  = l >> 4;
    const int row = blockIdx.x * 64 + w * 16 + lr;
    constexpr int NKC = (K + 31) / 32;

    f32x4 acc[8];
    #pragma unroll
    for (int ct = 0; ct < 8; ++ct) acc[ct] = (f32x4){0.f, 0.f, 0.f, 0.f};

    #pragma unroll
    for (int kc = 0; kc < NKC; ++kc) {
        U8 a;
        const int kb = kc * 32 + 4 * q;
        if (AF32) {
            const float* A = (const float*)Av + (size_t)row * K;
            f32x4 lo = (f32x4){0.f,0.f,0.f,0.f}, hi = (f32x4){0.f,0.f,0.f,0.f};
            if (kb < K)      lo = *(const f32x4*)(A + kb);
            if (kb + 16 < K) hi = *(const f32x4*)(A + kb + 16);
            #pragma unroll
            for (int i = 0; i < 4; ++i) {
                a.s[i]     = (short)f2bf(lo[i]);
                a.s[4 + i] = (short)f2bf(hi[i]);
            }
        } else {
            const u16* A = (const u16*)Av + (size_t)row * K;
            a.u[0] = (kb < K)      ? *(const u64*)(A + kb)      : 0ull;
            a.u[1] = (kb + 16 < K) ? *(const u64*)(A + kb + 16) : 0ull;
        }
        #pragma unroll
        for (int ct = 0; ct < 8; ++ct)
            acc[ct] = __builtin_amdgcn_mfma_f32_16x16x32_bf16(
                          a.v, wf[(kc * 8 + ct) * 64 + l], acc[ct], 0, 0, 0);
    }

    const int orow0 = blockIdx.x * 64 + w * 16 + 4 * q;
    #pragma unroll
    for (int ct = 0; ct < 8; ++ct) {
        const int col = ct * 16 + lr;
        const float b = bias[col];
        #pragma unroll
        for (int r = 0; r < 4; ++r) {
            float v = acc[ct][r] + b;
            if (RELU) v = fmaxf(v, 0.f);
            if (OUTF32) ((float*)Cv)[(size_t)(orow0 + r) * 128 + col] = v;
            else        ((u16*)Cv)[(size_t)(orow0 + r) * 128 + col] = f2bf(v);
        }
    }
}

// ---------------- column-sliced bf16 aggregation ----------------
// Slice = 32 cols = 4 MB source table (fits one XCD L2). 16 lanes x 4B per row;
// 8-deep independent u32 gathers; gridDim.y = slice (x-major dispatch keeps one
// slice resident at a time).
template<bool KW_SIDE>
__global__ __launch_bounds__(256) void aggs_k(
        const int* __restrict__ off, const int* __restrict__ cnt,
        const int* __restrict__ csr, const u16* __restrict__ gsrc,
        const u16* __restrict__ h0, const float* __restrict__ dis,
        u16* __restrict__ outb) {
    const int grp  = threadIdx.x >> 4;          // 16 row-groups
    const int lane = threadIdx.x & 15;
    const int r    = blockIdx.x * 16 + grp;
    const int col0 = blockIdx.y * 32;
    const int seg  = KW_SIDE ? r : (NKW + r);
    const int st = off[seg];
    const int n  = cnt[seg];
    const u16* gs = gsrc + col0 + lane * 2;

    float a0 = 0.f, a1 = 0.f;
    int i = 0;
    for (; i + 8 <= n; i += 8) {
        u32 v[8];
        #pragma unroll
        for (int k = 0; k < 8; ++k) {
            int nb = csr[st + i + k];           // same addr across 16 lanes (broadcast)
            v[k] = *(const u32*)(gs + (size_t)nb * 128);
        }
        #pragma unroll
        for (int k = 0; k < 8; ++k) {
            a0 += bf2f((u16)v[k]);
            a1 += bf2f((u16)(v[k] >> 16));
        }
    }
    for (; i < n; ++i) {
        int nb = csr[st + i];
        u32 v = *(const u32*)(gs + (size_t)nb * 128);
        a0 += bf2f((u16)v);
        a1 += bf2f((u16)(v >> 16));
    }

    const float dk = dis[seg];
    if (KW_SIDE) {   // t = dk*(sum + dk*h0)
        u32 h = *(const u32*)(h0 + (size_t)r * 128 + col0 + lane * 2);
        a0 = dk * (a0 + dk * bf2f((u16)h));
        a1 = dk * (a1 + dk * bf2f((u16)(h >> 16)));
    } else {         // pre-scale by dis_doc (commutes with the GEMM)
        a0 *= dk;
        a1 *= dk;
    }
    u32 ov = (u32)f2bf(a0) | ((u32)f2bf(a1) << 16);
    *(u32*)(outb + (size_t)r * 128 + col0 + lane * 2) = ov;
}

// ---------------- fused gates: out_doc = xdoc * xf * xt ----------------
__global__ __launch_bounds__(256) void gates_k(
        const float* __restrict__ Xfb, const float* __restrict__ Xt,
        const short8* __restrict__ wf1, const short8* __restrict__ wf2,
        const short8* __restrict__ wt1, const short8* __restrict__ wt2,
        const float* __restrict__ bf1v, const float* __restrict__ bf2v,
        const float* __restrict__ bt1v, const float* __restrict__ bt2v,
        const u16* __restrict__ xdoc, float* __restrict__ outdoc) {
    const int tid = threadIdx.x;
    const int w = tid >> 6, l = tid & 63, lr = l & 15, q = l >> 4;
    const int row0 = blockIdx.x * 64 + w * 16;      // wave's 16 doc rows

    f32x4 accf[8], acct[8];

    // ===== feedback gate =====
    {
        U8 bfrag;
        f32x4 x = *(const f32x4*)(Xfb + (size_t)(row0 + lr) * 16 + 4 * q);
        #pragma unroll
        for (int i = 0; i < 4; ++i) { bfrag.s[i] = (short)f2bf(x[i]); bfrag.s[4+i] = 0; }
        f32x4 s1[8];
        #pragma unroll
        for (int mt = 0; mt < 8; ++mt) {
            s1[mt] = __builtin_amdgcn_mfma_f32_16x16x32_bf16(
                         wf1[mt * 64 + l], bfrag.v, (f32x4){0.f,0.f,0.f,0.f}, 0, 0, 0);
            f32x4 bb = *(const f32x4*)(bf1v + mt * 16 + 4 * q);
            #pragma unroll
            for (int rr = 0; rr < 4; ++rr) s1[mt][rr] = fmaxf(s1[mt][rr] + bb[rr], 0.f);
        }
        #pragma unroll
        for (int ct = 0; ct < 8; ++ct) accf[ct] = (f32x4){0.f,0.f,0.f,0.f};
        #pragma unroll
        for (int kc = 0; kc < 4; ++kc) {
            U8 af;
            #pragma unroll
            for (int i = 0; i < 8; ++i) af.s[i] = (short)f2bf(s1[2*kc + (i>>2)][i & 3]);
            #pragma unroll
            for (int ct = 0; ct < 8; ++ct)
                accf[ct] = __builtin_amdgcn_mfma_f32_16x16x32_bf16(
                               af.v, wf2[(kc * 8 + ct) * 64 + l], accf[ct], 0, 0, 0);
        }
    }
    // ===== time gate =====
    {
        U8 bfrag;
        #pragma unroll
        for (int i = 0; i < 8; ++i) bfrag.s[i] = 0;
        if (q < 2) {
            f32x4 x = *(const f32x4*)(Xt + (size_t)(row0 + lr) * 8 + 4 * q);
            #pragma unroll
            for (int i = 0; i < 4; ++i) bfrag.s[i] = (short)f2bf(x[i]);
        }
        f32x4 s1[8];
        #pragma unroll
        for (int mt = 0; mt < 8; ++mt) {
            s1[mt] = __builtin_amdgcn_mfma_f32_16x16x32_bf16(
                         wt1[mt * 64 + l], bfrag.v, (f32x4){0.f,0.f,0.f,0.f}, 0, 0, 0);
            f32x4 bb = *(const f32x4*)(bt1v + mt * 16 + 4 * q);
            #pragma unroll
            for (int rr = 0; rr < 4; ++rr) s1[mt][rr] = fmaxf(s1[mt][rr] + bb[rr], 0.f);
        }
        #pragma unroll
        for (int ct = 0; ct < 8; ++ct) acct[ct] = (f32x4){0.f,0.f,0.f,0.f};
        #pragma unroll
        for (int kc = 0; kc < 4; ++kc) {
            U8 af;
            #pragma unroll
            for (int i = 0; i < 8; ++i) af.s[i] = (short)f2bf(s1[2*kc + (i>>2)][i & 3]);
            #pragma unroll
            for (int ct = 0; ct < 8; ++ct)
                acct[ct] = __builtin_amdgcn_mfma_f32_16x16x32_bf16(
                               af.v, wt2[(kc * 8 + ct) * 64 + l], acct[ct], 0, 0, 0);
        }
    }
    // ===== epilogue: out = xdoc * xf * xt =====
    const int orow0 = row0 + 4 * q;
    #pragma unroll
    for (int ct = 0; ct < 8; ++ct) {
        const int col = ct * 16 + lr;
        const float b2f = bf2v[col];
        const float b2t = bt2v[col];
        #pragma unroll
        for (int rr = 0; rr < 4; ++rr) {
            const size_t idx = (size_t)(orow0 + rr) * 128 + col;
            float xd = bf2f(xdoc[idx]);
            outdoc[idx] = xd * (accf[ct][rr] + b2f) * (acct[ct][rr] + b2t);
        }
    }
}

extern "C" void kernel_launch(void* const* d_in, const int* in_sizes, int n_in,
                              void* d_out, int out_size, void* d_ws, size_t ws_size,
                              hipStream_t stream) {
    const float* Xn  = (const float*)d_in[0];
    const float* Xfb = (const float*)d_in[1];
    const float* Xt  = (const float*)d_in[2];
    const int*   e01 = (const int*)d_in[3];
    const float* W0  = (const float*)d_in[6];
    const float* b0  = (const float*)d_in[7];
    const float* Wg1 = (const float*)d_in[8];
    const float* bg1 = (const float*)d_in[9];
    const float* Wg2 = (const float*)d_in[10];
    const float* bg2 = (const float*)d_in[11];
    const float* Wf1 = (const float*)d_in[12];
    const float* bf1 = (const float*)d_in[13];
    const float* Wf2 = (const float*)d_in[14];
    const float* bf2 = (const float*)d_in[15];
    const float* Wt1 = (const float*)d_in[16];
    const float* bt1 = (const float*)d_in[17];
    const float* Wt2 = (const float*)d_in[18];
    const float* bt2 = (const float*)d_in[19];

    float* out = (float*)d_out;
    char*  ws  = (char*)d_ws;
    u16*   bufA  = (u16*)(ws + BUFA_OFF);     // h0 bf16
    u32*   pairs = (u32*)(ws + BUFA_OFF);     // alias: dead before bufA first written
    u16*   bufB  = (u16*)(ws + BUFB_OFF);     // agg out bf16
    u16*   bufC  = (u16*)(ws + BUFC_OFF);     // xdoc bf16
    short8* wfb  = (short8*)(ws + WF_OFF);
    int*   csr   = (int*)(ws + CSR_OFF);
    int*   cnt   = (int*)(ws + CNT_OFF);
    int*   bhist = (int*)(ws + AUX_OFF);
    int*   bfill = bhist + 512;
    int*   bbase = bhist + 1024;
    int*   off   = (int*)(ws + OFF_OFF);
    float* dis   = (float*)(ws + DIS_OFF);

    const int* src = e01;
    const int* dst = e01 + NE;

    PrepArgs pa;
    pa.w[0] = W0;  pa.K[0] = 128;
    pa.w[1] = Wg1; pa.K[1] = 128;
    pa.w[2] = Wg2; pa.K[2] = 128;
    pa.w[3] = Wf1; pa.K[3] = 16;
    pa.w[4] = Wf2; pa.K[4] = 128;
    pa.w[5] = Wt1; pa.K[5] = 8;
    pa.w[6] = Wt2; pa.K[6] = 128;
    prepw_k<<<224, 64, 0, stream>>>(pa, wfb);

    // bucketed CSR build
    hipMemsetAsync(bhist, 0, 4096, stream);
    bhist_k<<<NBLK, 256, 0, stream>>>(src, dst, bhist);
    bscan_k<<<1, 512, 0, stream>>>(bhist, bbase);
    part_k <<<NBLK, 256, 0, stream>>>(src, dst, bbase, bfill, pairs);
    build_k<<<512, 256, 0, stream>>>(pairs, bbase, bfill, off, cnt, dis, csr);

    // layer 0: h0 = relu(Xn[:NKW] @ W0 + b0)
    mgemm_k<128, true,  true,  false><<<1024, 256, 0, stream>>>(Xn, wfb + 0*2048, b0, bufA);

    // layer 1: aggB = dis_doc * sum h0[src] ; xdoc = relu(aggB @ Wg1 + bg1)
    aggs_k<false><<<dim3(NDOC / 16, 4), 256, 0, stream>>>(off, cnt, csr, bufA, nullptr, dis, bufB);
    mgemm_k<128, false, true,  false><<<1024, 256, 0, stream>>>(bufB, wfb + 1*2048, bg1, bufC);

    // layer 2: aggB = dk*(sum xdoc[d] + dk*h0) ; out_kw = relu(aggB @ Wg2 + bg2) fp32
    aggs_k<true><<<dim3(NKW / 16, 4), 256, 0, stream>>>(off, cnt, csr, bufC, bufA, dis, bufB);
    mgemm_k<128, false, true,  true ><<<1024, 256, 0, stream>>>(bufB, wfb + 2*2048, bg2, out);

    // fused gates + final multiply (reads xdoc=bufC)
    gates_k<<<1024, 256, 0, stream>>>(Xfb, Xt,
                                      wfb + 3*2048, wfb + 4*2048, wfb + 5*2048, wfb + 6*2048,
                                      bf1, bf2, bt1, bt2,
                                      bufC, out + (size_t)NKW * 128);
}

// Round 6
// 197.536 us; speedup vs baseline: 1.2725x; 1.2725x over previous
//
#include <hip/hip_runtime.h>

#define NKW   65536
#define NDOC  65536
#define NSEG  131072          // kw segs then doc segs
#define NE    1048576
#define CHUNK 4096            // edges per partition block
#define NBLK  (NE / CHUNK)    // 256

typedef unsigned long long u64;
typedef unsigned short     u16;
typedef unsigned int       u32;

typedef __attribute__((ext_vector_type(8))) short short8;   // 8 bf16 (4 VGPRs)
typedef __attribute__((ext_vector_type(4))) float f32x4;    // MFMA acc

union U8 { short8 v; u64 u[2]; short s[8]; };

__device__ __forceinline__ u16 f2bf(float f) {              // RNE f32->bf16
    u32 u = __builtin_bit_cast(u32, f);
    u = (u + 0x7fffu + ((u >> 16) & 1u)) >> 16;
    return (u16)u;
}
__device__ __forceinline__ float bf2f(u16 h) {
    return __builtin_bit_cast(float, (u32)h << 16);
}

// ---------------- workspace layout (bytes) ----------------
#define BUFA_OFF 0ull
#define BUFB_OFF 16777216ull
#define BUFC_OFF 33554432ull
#define WF_OFF   50331648ull            // 7 * 32KB fragment-packed weights
#define CSR_OFF  51380224ull            // 2*NE ints = 8 MB
#define CNT_OFF  59768832ull            // NSEG ints
#define AUX_OFF  60293120ull            // bhist[512] | bfill[512] | bbase[512]
#define OFF_OFF  60821504ull            // NSEG ints
#define DIS_OFF  61345792ull            // NSEG floats

// ---------------- CSR build (bucketed, write-local) ----------------
__global__ __launch_bounds__(256) void bhist_k(const int* __restrict__ src,
                                               const int* __restrict__ dst,
                                               int* __restrict__ bhist) {
    __shared__ int h[512];
    int tid = threadIdx.x;
    for (int i = tid; i < 512; i += 256) h[i] = 0;
    __syncthreads();
    int e0 = blockIdx.x * CHUNK;
    for (int i = tid; i < CHUNK; i += 256) {
        int s = src[e0 + i];
        int d = dst[e0 + i] - NKW;
        atomicAdd(&h[s >> 8], 1);
        atomicAdd(&h[256 + (d >> 8)], 1);
    }
    __syncthreads();
    for (int i = tid; i < 512; i += 256)
        if (h[i]) atomicAdd(&bhist[i], h[i]);
}

__global__ void bscan_k(const int* __restrict__ bhist, int* __restrict__ bbase) {
    __shared__ int s[512];
    int tid = threadIdx.x;
    int v = bhist[tid];
    s[tid] = v;
    __syncthreads();
    for (int d = 1; d < 512; d <<= 1) {
        int t = (tid >= d) ? s[tid - d] : 0;
        __syncthreads();
        s[tid] += t;
        __syncthreads();
    }
    bbase[tid] = s[tid] - v;      // exclusive
}

__global__ __launch_bounds__(256) void part_k(const int* __restrict__ src,
                                              const int* __restrict__ dst,
                                              const int* __restrict__ bbase,
                                              int* __restrict__ bfill,
                                              u32* __restrict__ pairs) {
    __shared__ int h[512], sc[512], base[512];
    __shared__ u32 staged[2 * CHUNK];
    const int tid = threadIdx.x;
    for (int i = tid; i < 512; i += 256) h[i] = 0;
    __syncthreads();

    const int e0 = blockIdx.x * CHUNK;
    int se[16], de[16];
    #pragma unroll
    for (int j = 0; j < 16; ++j) {
        int e = e0 + tid + j * 256;           // coalesced
        se[j] = src[e];
        de[j] = dst[e] - NKW;
        atomicAdd(&h[se[j] >> 8], 1);
        atomicAdd(&h[256 + (de[j] >> 8)], 1);
    }
    __syncthreads();

    sc[tid] = h[tid];
    __syncthreads();
    for (int d = 1; d < 256; d <<= 1) {
        int t = (tid >= d) ? sc[tid - d] : 0;
        __syncthreads();
        sc[tid] += t;
        __syncthreads();
    }
    sc[256 + tid] = h[256 + tid];
    __syncthreads();
    for (int d = 1; d < 256; d <<= 1) {
        int t = (tid >= d) ? sc[256 + tid - d] : 0;
        __syncthreads();
        sc[256 + tid] += t;
        __syncthreads();
    }

    for (int i = tid; i < 512; i += 256) {
        base[i] = bbase[i] + atomicAdd(&bfill[i], h[i]);
        sc[i] -= h[i];
        h[i] = 0;
    }
    __syncthreads();

    #pragma unroll
    for (int j = 0; j < 16; ++j) {
        int bk = se[j] >> 8;
        int r  = atomicAdd(&h[bk], 1);
        staged[sc[bk] + r] = ((u32)(se[j] & 255) << 16) | (u32)de[j];
        int bd = 256 + (de[j] >> 8);
        int r2 = atomicAdd(&h[bd], 1);
        staged[CHUNK + sc[bd] + r2] = ((u32)(de[j] & 255) << 16) | (u32)se[j];
    }
    __syncthreads();

    for (int i = tid; i < 512; i += 256) {
        int n = h[i];
        int so = (i < 256 ? 0 : CHUNK) + sc[i];
        u32* dp = pairs + base[i];
        for (int j = 0; j < n; ++j) dp[j] = staged[so + j];
    }
}

__global__ __launch_bounds__(256) void build_k(const u32* __restrict__ pairs,
                                               const int* __restrict__ bbase,
                                               const int* __restrict__ bfill,
                                               int* __restrict__ off, int* __restrict__ cnt,
                                               float* __restrict__ dis, int* __restrict__ csr) {
    __shared__ int lcnt[256], lsc[256];
    const int b   = blockIdx.x;
    const int tid = threadIdx.x;
    const int start = bbase[b];
    const int size  = bfill[b];
    lcnt[tid] = 0;
    __syncthreads();
    for (int i = tid; i < size; i += 256)
        atomicAdd(&lcnt[(pairs[start + i] >> 16) & 255], 1);
    __syncthreads();
    lsc[tid] = lcnt[tid];
    __syncthreads();
    for (int d = 1; d < 256; d <<= 1) {
        int t = (tid >= d) ? lsc[tid - d] : 0;
        __syncthreads();
        lsc[tid] += t;
        __syncthreads();
    }
    const int myexc = lsc[tid] - lcnt[tid];
    const int seg = (b < 256) ? (b * 256 + tid) : (NKW + (b - 256) * 256 + tid);
    off[seg] = start + myexc;
    cnt[seg] = lcnt[tid];
    dis[seg] = rsqrtf((float)(lcnt[tid] + 1));
    lsc[tid]  = myexc;
    lcnt[tid] = 0;
    __syncthreads();
    for (int i = tid; i < size; i += 256) {
        u32 p = pairs[start + i];
        int key = (p >> 16) & 255;
        int r = atomicAdd(&lcnt[key], 1);
        csr[start + lsc[key] + r] = (int)(p & 0xFFFF);
    }
}

// ---------------- weight fragment pre-pack (fp32 [K][128] -> bf16 MFMA frags) ----
struct PrepArgs { const float* w[7]; int K[7]; };

__global__ void prepw_k(PrepArgs pa, short8* __restrict__ outb) {
    int m  = blockIdx.x >> 5;
    int bk = blockIdx.x & 31;
    int kc = bk >> 3, ct = bk & 7;
    int l  = threadIdx.x;
    int K  = pa.K[m];
    const float* W = pa.w[m];
    U8 o;
    #pragma unroll
    for (int i = 0; i < 8; ++i) {
        int k   = kc * 32 + 4 * (l >> 4) + (i & 3) + 16 * (i >> 2);
        int col = ct * 16 + (l & 15);
        float v = (k < K) ? W[(size_t)k * 128 + col] : 0.f;
        o.s[i] = (short)f2bf(v);
    }
    outb[(size_t)m * 2048 + bk * 64 + l] = o.v;
}

// ---------------- MFMA GEMM: C[65536,128] = op(A[65536,K] @ W[K,128] + b) --------
template<int K, bool AF32, bool RELU, bool OUTF32>
__global__ __launch_bounds__(256) void mgemm_k(
        const void* __restrict__ Av, const short8* __restrict__ wf,
        const float* __restrict__ bias, void* __restrict__ Cv) {
    const int tid = threadIdx.x;
    const int w  = tid >> 6;
    const int l  = tid & 63;
    const int lr = l & 15;
    const int q  = l >> 4;
    const int row = blockIdx.x * 64 + w * 16 + lr;
    constexpr int NKC = (K + 31) / 32;

    f32x4 acc[8];
    #pragma unroll
    for (int ct = 0; ct < 8; ++ct) acc[ct] = (f32x4){0.f, 0.f, 0.f, 0.f};

    #pragma unroll
    for (int kc = 0; kc < NKC; ++kc) {
        U8 a;
        const int kb = kc * 32 + 4 * q;
        if (AF32) {
            const float* A = (const float*)Av + (size_t)row * K;
            f32x4 lo = (f32x4){0.f,0.f,0.f,0.f}, hi = (f32x4){0.f,0.f,0.f,0.f};
            if (kb < K)      lo = *(const f32x4*)(A + kb);
            if (kb + 16 < K) hi = *(const f32x4*)(A + kb + 16);
            #pragma unroll
            for (int i = 0; i < 4; ++i) {
                a.s[i]     = (short)f2bf(lo[i]);
                a.s[4 + i] = (short)f2bf(hi[i]);
            }
        } else {
            const u16* A = (const u16*)Av + (size_t)row * K;
            a.u[0] = (kb < K)      ? *(const u64*)(A + kb)      : 0ull;
            a.u[1] = (kb + 16 < K) ? *(const u64*)(A + kb + 16) : 0ull;
        }
        #pragma unroll
        for (int ct = 0; ct < 8; ++ct)
            acc[ct] = __builtin_amdgcn_mfma_f32_16x16x32_bf16(
                          a.v, wf[(kc * 8 + ct) * 64 + l], acc[ct], 0, 0, 0);
    }

    const int orow0 = blockIdx.x * 64 + w * 16 + 4 * q;
    #pragma unroll
    for (int ct = 0; ct < 8; ++ct) {
        const int col = ct * 16 + lr;
        const float b = bias[col];
        #pragma unroll
        for (int r = 0; r < 4; ++r) {
            float v = acc[ct][r] + b;
            if (RELU) v = fmaxf(v, 0.f);
            if (OUTF32) ((float*)Cv)[(size_t)(orow0 + r) * 128 + col] = v;
            else        ((u16*)Cv)[(size_t)(orow0 + r) * 128 + col] = f2bf(v);
        }
    }
}

// ---------------- bf16 neighborhood aggregation ----------------
// 8 rows/block, 32 lanes/row (full 256B line per edge), 8-deep gather pipeline.
template<bool KW_SIDE>
__global__ __launch_bounds__(256) void aggb_k(
        const int* __restrict__ off, const int* __restrict__ cnt,
        const int* __restrict__ csr, const u16* __restrict__ gsrc,
        const u16* __restrict__ h0, const float* __restrict__ dis,
        u16* __restrict__ outb) {
    int r    = blockIdx.x * 8 + (threadIdx.x >> 5);
    int lane = threadIdx.x & 31;
    int seg  = KW_SIDE ? r : (NKW + r);
    int st = off[seg];
    int n  = cnt[seg];
    float a0 = 0.f, a1 = 0.f, a2 = 0.f, a3 = 0.f;
    #define ACC4(vv) { a0 += bf2f((u16)(vv)); a1 += bf2f((u16)((vv) >> 16)); \
                       a2 += bf2f((u16)((vv) >> 32)); a3 += bf2f((u16)((vv) >> 48)); }
    int i = 0;
    for (; i + 8 <= n; i += 8) {                  // 8 gathers in flight (2KB/group)
        int nb[8];
        #pragma unroll
        for (int k = 0; k < 8; ++k) nb[k] = csr[st + i + k];
        u64 v[8];
        #pragma unroll
        for (int k = 0; k < 8; ++k)
            v[k] = *(const u64*)(gsrc + (size_t)nb[k] * 128 + lane * 4);
        #pragma unroll
        for (int k = 0; k < 8; ++k) ACC4(v[k])
    }
    for (; i < n; ++i) {
        int nb = csr[st + i];
        u64 v = *(const u64*)(gsrc + (size_t)nb * 128 + lane * 4);
        ACC4(v)
    }
    #undef ACC4
    float dk = dis[seg];
    if (KW_SIDE) {   // t = dk*(sum + dk*h0)
        u64 h = *(const u64*)(h0 + (size_t)r * 128 + lane * 4);
        a0 = dk * (a0 + dk * bf2f((u16)h));
        a1 = dk * (a1 + dk * bf2f((u16)(h >> 16)));
        a2 = dk * (a2 + dk * bf2f((u16)(h >> 32)));
        a3 = dk * (a3 + dk * bf2f((u16)(h >> 48)));
    } else {         // pre-scale by dis_doc (commutes with the GEMM)
        a0 *= dk; a1 *= dk; a2 *= dk; a3 *= dk;
    }
    u64 ov = (u64)f2bf(a0) | ((u64)f2bf(a1) << 16) |
             ((u64)f2bf(a2) << 32) | ((u64)f2bf(a3) << 48);
    *(u64*)(outb + (size_t)r * 128 + lane * 4) = ov;
}

// ---------------- fused gates: out_doc = xdoc * xf * xt ----------------
__global__ __launch_bounds__(256) void gates_k(
        const float* __restrict__ Xfb, const float* __restrict__ Xt,
        const short8* __restrict__ wf1, const short8* __restrict__ wf2,
        const short8* __restrict__ wt1, const short8* __restrict__ wt2,
        const float* __restrict__ bf1v, const float* __restrict__ bf2v,
        const float* __restrict__ bt1v, const float* __restrict__ bt2v,
        const u16* __restrict__ xdoc, float* __restrict__ outdoc) {
    const int tid = threadIdx.x;
    const int w = tid >> 6, l = tid & 63, lr = l & 15, q = l >> 4;
    const int row0 = blockIdx.x * 64 + w * 16;      // wave's 16 doc rows

    f32x4 accf[8], acct[8];

    // ===== feedback gate =====
    {
        U8 bfrag;
        f32x4 x = *(const f32x4*)(Xfb + (size_t)(row0 + lr) * 16 + 4 * q);
        #pragma unroll
        for (int i = 0; i < 4; ++i) { bfrag.s[i] = (short)f2bf(x[i]); bfrag.s[4+i] = 0; }
        f32x4 s1[8];
        #pragma unroll
        for (int mt = 0; mt < 8; ++mt) {
            s1[mt] = __builtin_amdgcn_mfma_f32_16x16x32_bf16(
                         wf1[mt * 64 + l], bfrag.v, (f32x4){0.f,0.f,0.f,0.f}, 0, 0, 0);
            f32x4 bb = *(const f32x4*)(bf1v + mt * 16 + 4 * q);
            #pragma unroll
            for (int rr = 0; rr < 4; ++rr) s1[mt][rr] = fmaxf(s1[mt][rr] + bb[rr], 0.f);
        }
        #pragma unroll
        for (int ct = 0; ct < 8; ++ct) accf[ct] = (f32x4){0.f,0.f,0.f,0.f};
        #pragma unroll
        for (int kc = 0; kc < 4; ++kc) {
            U8 af;
            #pragma unroll
            for (int i = 0; i < 8; ++i) af.s[i] = (short)f2bf(s1[2*kc + (i>>2)][i & 3]);
            #pragma unroll
            for (int ct = 0; ct < 8; ++ct)
                accf[ct] = __builtin_amdgcn_mfma_f32_16x16x32_bf16(
                               af.v, wf2[(kc * 8 + ct) * 64 + l], accf[ct], 0, 0, 0);
        }
    }
    // ===== time gate =====
    {
        U8 bfrag;
        #pragma unroll
        for (int i = 0; i < 8; ++i) bfrag.s[i] = 0;
        if (q < 2) {
            f32x4 x = *(const f32x4*)(Xt + (size_t)(row0 + lr) * 8 + 4 * q);
            #pragma unroll
            for (int i = 0; i < 4; ++i) bfrag.s[i] = (short)f2bf(x[i]);
        }
        f32x4 s1[8];
        #pragma unroll
        for (int mt = 0; mt < 8; ++mt) {
            s1[mt] = __builtin_amdgcn_mfma_f32_16x16x32_bf16(
                         wt1[mt * 64 + l], bfrag.v, (f32x4){0.f,0.f,0.f,0.f}, 0, 0, 0);
            f32x4 bb = *(const f32x4*)(bt1v + mt * 16 + 4 * q);
            #pragma unroll
            for (int rr = 0; rr < 4; ++rr) s1[mt][rr] = fmaxf(s1[mt][rr] + bb[rr], 0.f);
        }
        #pragma unroll
        for (int ct = 0; ct < 8; ++ct) acct[ct] = (f32x4){0.f,0.f,0.f,0.f};
        #pragma unroll
        for (int kc = 0; kc < 4; ++kc) {
            U8 af;
            #pragma unroll
            for (int i = 0; i < 8; ++i) af.s[i] = (short)f2bf(s1[2*kc + (i>>2)][i & 3]);
            #pragma unroll
            for (int ct = 0; ct < 8; ++ct)
                acct[ct] = __builtin_amdgcn_mfma_f32_16x16x32_bf16(
                               af.v, wt2[(kc * 8 + ct) * 64 + l], acct[ct], 0, 0, 0);
        }
    }
    // ===== epilogue: out = xdoc * xf * xt =====
    const int orow0 = row0 + 4 * q;
    #pragma unroll
    for (int ct = 0; ct < 8; ++ct) {
        const int col = ct * 16 + lr;
        const float b2f = bf2v[col];
        const float b2t = bt2v[col];
        #pragma unroll
        for (int rr = 0; rr < 4; ++rr) {
            const size_t idx = (size_t)(orow0 + rr) * 128 + col;
            float xd = bf2f(xdoc[idx]);
            outdoc[idx] = xd * (accf[ct][rr] + b2f) * (acct[ct][rr] + b2t);
        }
    }
}

extern "C" void kernel_launch(void* const* d_in, const int* in_sizes, int n_in,
                              void* d_out, int out_size, void* d_ws, size_t ws_size,
                              hipStream_t stream) {
    const float* Xn  = (const float*)d_in[0];
    const float* Xfb = (const float*)d_in[1];
    const float* Xt  = (const float*)d_in[2];
    const int*   e01 = (const int*)d_in[3];
    const float* W0  = (const float*)d_in[6];
    const float* b0  = (const float*)d_in[7];
    const float* Wg1 = (const float*)d_in[8];
    const float* bg1 = (const float*)d_in[9];
    const float* Wg2 = (const float*)d_in[10];
    const float* bg2 = (const float*)d_in[11];
    const float* Wf1 = (const float*)d_in[12];
    const float* bf1 = (const float*)d_in[13];
    const float* Wf2 = (const float*)d_in[14];
    const float* bf2 = (const float*)d_in[15];
    const float* Wt1 = (const float*)d_in[16];
    const float* bt1 = (const float*)d_in[17];
    const float* Wt2 = (const float*)d_in[18];
    const float* bt2 = (const float*)d_in[19];

    float* out = (float*)d_out;
    char*  ws  = (char*)d_ws;
    u16*   bufA  = (u16*)(ws + BUFA_OFF);     // h0 bf16
    u32*   pairs = (u32*)(ws + BUFA_OFF);     // alias: dead before bufA first written
    u16*   bufB  = (u16*)(ws + BUFB_OFF);     // agg out bf16
    u16*   bufC  = (u16*)(ws + BUFC_OFF);     // xdoc bf16
    short8* wfb  = (short8*)(ws + WF_OFF);
    int*   csr   = (int*)(ws + CSR_OFF);
    int*   cnt   = (int*)(ws + CNT_OFF);
    int*   bhist = (int*)(ws + AUX_OFF);
    int*   bfill = bhist + 512;
    int*   bbase = bhist + 1024;
    int*   off   = (int*)(ws + OFF_OFF);
    float* dis   = (float*)(ws + DIS_OFF);

    const int* src = e01;
    const int* dst = e01 + NE;

    PrepArgs pa;
    pa.w[0] = W0;  pa.K[0] = 128;
    pa.w[1] = Wg1; pa.K[1] = 128;
    pa.w[2] = Wg2; pa.K[2] = 128;
    pa.w[3] = Wf1; pa.K[3] = 16;
    pa.w[4] = Wf2; pa.K[4] = 128;
    pa.w[5] = Wt1; pa.K[5] = 8;
    pa.w[6] = Wt2; pa.K[6] = 128;
    prepw_k<<<224, 64, 0, stream>>>(pa, wfb);

    // bucketed CSR build
    hipMemsetAsync(bhist, 0, 4096, stream);
    bhist_k<<<NBLK, 256, 0, stream>>>(src, dst, bhist);
    bscan_k<<<1, 512, 0, stream>>>(bhist, bbase);
    part_k <<<NBLK, 256, 0, stream>>>(src, dst, bbase, bfill, pairs);
    build_k<<<512, 256, 0, stream>>>(pairs, bbase, bfill, off, cnt, dis, csr);

    // layer 0: h0 = relu(Xn[:NKW] @ W0 + b0)
    mgemm_k<128, true,  true,  false><<<1024, 256, 0, stream>>>(Xn, wfb + 0*2048, b0, bufA);

    // layer 1: aggB = dis_doc * sum h0[src] ; xdoc = relu(aggB @ Wg1 + bg1)
    aggb_k<false><<<NDOC / 8, 256, 0, stream>>>(off, cnt, csr, bufA, nullptr, dis, bufB);
    mgemm_k<128, false, true,  false><<<1024, 256, 0, stream>>>(bufB, wfb + 1*2048, bg1, bufC);

    // layer 2: aggB = dk*(sum xdoc[d] + dk*h0) ; out_kw = relu(aggB @ Wg2 + bg2) fp32
    aggb_k<true><<<NKW / 8, 256, 0, stream>>>(off, cnt, csr, bufC, bufA, dis, bufB);
    mgemm_k<128, false, true,  true ><<<1024, 256, 0, stream>>>(bufB, wfb + 2*2048, bg2, out);

    // fused gates + final multiply (reads xdoc=bufC)
    gates_k<<<1024, 256, 0, stream>>>(Xfb, Xt,
                                      wfb + 3*2048, wfb + 4*2048, wfb + 5*2048, wfb + 6*2048,
                                      bf1, bf2, bt1, bt2,
                                      bufC, out + (size_t)NKW * 128);
}